// Round 4
// baseline (905.566 us; speedup 1.0000x reference)
//
#include <hip/hip_runtime.h>
#include <hip/hip_bf16.h>

// AxialAttention on MI355X — bf16 MFMA pipeline, fully coalesced memory.
// T0: transpose x [n0][c][s][w] fp32 -> Y [n0][w][s][c] bf16 (LDS tile transpose).
// K1: per (n0,w): contiguous 32KB y load; per head: VALU QKV -> E^T (mfma 32x32x16)
//     -> in-register softmax sums -> PV^T (mfma 16x16x32) -> AO into aliased y_s LDS;
//     one contiguous 32KB AO store at the end.
// K2: out-proj per (n0,s): Wo staged in LDS bf16; D = Wo*AO^T via mfma 32x32x16.

typedef __attribute__((ext_vector_type(8)))  short bf16x8;
typedef __attribute__((ext_vector_type(4)))  float f32x4;
typedef __attribute__((ext_vector_type(16))) float f32x16;

__device__ __forceinline__ float bf2f(unsigned short u) {
    union { unsigned int i; float f; } c; c.i = ((unsigned int)u) << 16; return c.f;
}
__device__ __forceinline__ unsigned short f2bf(float f) {
    union { __hip_bfloat16 h; unsigned short u; } c; c.h = __float2bfloat16(f); return c.u;
}

#define INV_SCALE 0.088388347648318447f   // 1/sqrt(128)

// ---------------- T0: x -> Y (bf16, transposed) ----------------
__global__ __launch_bounds__(256) void axattn_transpose(
    const float* __restrict__ x,
    unsigned short* __restrict__ Y)
{
    int n0 = blockIdx.x >> 7;
    int s  = blockIdx.x & 127;
    __shared__ unsigned int t_s[128][65];   // [w][c_pair], 2 bf16 packed; pad 65 -> 4-way max

    int tid = threadIdx.x;
    int wl  = tid & 31;      // float4 index along w
    int g   = tid >> 5;      // c-group (16 c each)

    const float* xp = x + ((size_t)(n0 * 128 + 16 * g) * 128 + s) * 128 + 4 * wl;
    #pragma unroll
    for (int i = 0; i < 16; i += 2) {
        float4 a = *(const float4*)(xp + (size_t)(i + 0) * 16384);
        float4 b = *(const float4*)(xp + (size_t)(i + 1) * 16384);
        int cp = 8 * g + (i >> 1);
        t_s[4 * wl + 0][cp] = (unsigned)f2bf(a.x) | ((unsigned)f2bf(b.x) << 16);
        t_s[4 * wl + 1][cp] = (unsigned)f2bf(a.y) | ((unsigned)f2bf(b.y) << 16);
        t_s[4 * wl + 2][cp] = (unsigned)f2bf(a.z) | ((unsigned)f2bf(b.z) << 16);
        t_s[4 * wl + 3][cp] = (unsigned)f2bf(a.w) | ((unsigned)f2bf(b.w) << 16);
    }
    __syncthreads();

    #pragma unroll
    for (int i = 0; i < 8; ++i) {
        int idx = tid + 256 * i;
        int w   = idx >> 4;
        int cp4 = idx & 15;
        uint4 v;
        v.x = t_s[w][4 * cp4 + 0];
        v.y = t_s[w][4 * cp4 + 1];
        v.z = t_s[w][4 * cp4 + 2];
        v.w = t_s[w][4 * cp4 + 3];
        *(uint4*)(Y + (((size_t)(n0 * 128 + w) * 128) + s) * 128 + 8 * cp4) = v;
    }
}

// ---------------- K1: QKV + attention ----------------
__global__ __launch_bounds__(256, 2) void axattn_qkvattn(
    const unsigned short* __restrict__ Y,
    const float* __restrict__ Wq,
    const float* __restrict__ Wk,
    const float* __restrict__ Wv,
    unsigned short* __restrict__ AO)   // bf16 [b][s][c], contiguous 32KB per block
{
    __shared__ __align__(16) unsigned short y_s[128][136];  // [s][c]; AO aliased per head
    __shared__ __align__(16) unsigned short q_s[128][24];   // [s][e]
    __shared__ __align__(16) unsigned short k_s[128][24];   // [s][e]
    __shared__ __align__(16) unsigned short vT_s[16][136];  // [d][j]
    __shared__ __align__(16) unsigned short pT_s[4][32][40];// per-wave [s_local][j_local]

    int n0 = blockIdx.x >> 7;
    int w  = blockIdx.x & 127;

    int tid  = threadIdx.x;
    int lane = tid & 63;
    int wi   = tid >> 6;

    // ---- stage y (contiguous, coalesced b128) ----
    const unsigned short* yb = Y + (size_t)(n0 * 128 + w) * 128 * 128;
    #pragma unroll
    for (int i = 0; i < 8; ++i) {
        int idx = tid + 256 * i;             // idx*8 = s*128 + 8*c8
        *(int4*)&y_s[idx >> 4][8 * (idx & 15)] = *(const int4*)(yb + (size_t)idx * 8);
    }
    __syncthreads();

    for (int h = 0; h < 8; ++h) {
        // ---- QKV (VALU): thread -> (s = tid&127, eh = tid>>7 wave-uniform) ----
        {
            int s  = tid & 127;
            int eh = tid >> 7;
            float yv[16];
            union { unsigned short u[8]; int4 v; } ya, yb2;
            ya.v  = *(const int4*)&y_s[s][16 * h];
            yb2.v = *(const int4*)&y_s[s][16 * h + 8];
            #pragma unroll
            for (int d = 0; d < 8; ++d) { yv[d] = bf2f(ya.u[d]); yv[d + 8] = bf2f(yb2.u[d]); }

            float qa[8], ka[8], va[8];
            #pragma unroll
            for (int j = 0; j < 8; ++j) { qa[j] = 0.f; ka[j] = 0.f; va[j] = 0.f; }
            #pragma unroll
            for (int d = 0; d < 16; ++d) {
                float yd = yv[d];
                #pragma unroll
                for (int j = 0; j < 8; ++j) {
                    int e = 8 * eh + j;
                    qa[j] = fmaf(yd, Wq[e * 16 + d], qa[j]);
                    ka[j] = fmaf(yd, Wk[e * 16 + d], ka[j]);
                    va[j] = fmaf(yd, Wv[e * 16 + d], va[j]);
                }
            }
            union { unsigned short u[8]; int4 v; } pq, pk;
            #pragma unroll
            for (int j = 0; j < 8; ++j) {
                pq.u[j] = f2bf(qa[j] * INV_SCALE);
                pk.u[j] = f2bf(ka[j]);
            }
            *(int4*)&q_s[s][8 * eh] = pq.v;
            *(int4*)&k_s[s][8 * eh] = pk.v;
            #pragma unroll
            for (int j = 0; j < 8; ++j) vT_s[8 * eh + j][s] = f2bf(va[j]);
        }
        __syncthreads();

        // ---- E^T = K * Q^T for this wave's 32 s-columns ----
        int sl = lane & 31;
        int kh = lane >> 5;
        bf16x8 qfrag = *(bf16x8*)&q_s[32 * wi + sl][8 * kh];

        f32x16 eacc[4];
        #pragma unroll
        for (int jt = 0; jt < 4; ++jt) {
            f32x16 z;
            #pragma unroll
            for (int i = 0; i < 16; ++i) z[i] = 0.f;
            bf16x8 kfrag = *(bf16x8*)&k_s[32 * jt + sl][8 * kh];
            eacc[jt] = __builtin_amdgcn_mfma_f32_32x32x16_bf16(kfrag, qfrag, z, 0, 0, 0);
        }

        // ---- softmax: exp in place, in-register row sums ----
        float s8[8];
        #pragma unroll
        for (int a = 0; a < 8; ++a) {
            float u = 0.f;
            #pragma unroll
            for (int b = 0; b < 8; ++b) {
                int jt = (a * 8 + b) >> 4, rg = (a * 8 + b) & 15;
                float p = __expf(eacc[jt][rg]);
                eacc[jt][rg] = p;
                u += p;
            }
            s8[a] = u;
        }
        float lsum = ((s8[0] + s8[1]) + (s8[2] + s8[3])) + ((s8[4] + s8[5]) + (s8[6] + s8[7]));
        lsum += __shfl_xor(lsum, 32, 64);
        float rl = 1.0f / lsum;

        // ---- PV^T via per-wave LDS slot ----
        f32x4 ao0, ao1;
        #pragma unroll
        for (int i = 0; i < 4; ++i) { ao0[i] = 0.f; ao1[i] = 0.f; }

        int qd = lane >> 4;
        #pragma unroll
        for (int jt = 0; jt < 4; ++jt) {
            #pragma unroll
            for (int a = 0; a < 4; ++a) {
                #pragma unroll
                for (int b = 0; b < 4; b += 2) {
                    int r0 = 4 * a + b;
                    unsigned int lo = f2bf(eacc[jt][r0]);
                    unsigned int hi = f2bf(eacc[jt][r0 + 1]);
                    int j0 = 8 * a + b + 4 * kh;
                    *(unsigned int*)&pT_s[wi][sl][j0] = lo | (hi << 16);
                }
            }
            bf16x8 afrag = *(bf16x8*)&vT_s[lane & 15][32 * jt + 8 * qd];
            bf16x8 b0 = *(bf16x8*)&pT_s[wi][lane & 15][8 * qd];
            bf16x8 b1 = *(bf16x8*)&pT_s[wi][16 + (lane & 15)][8 * qd];
            ao0 = __builtin_amdgcn_mfma_f32_16x16x32_bf16(afrag, b0, ao0, 0, 0, 0);
            ao1 = __builtin_amdgcn_mfma_f32_16x16x32_bf16(afrag, b1, ao1, 0, 0, 0);
        }

        // ---- scale by 1/l, write AO fragment into aliased y_s columns of head h ----
        // (y_s[:,16h:16h+16] was consumed by this head's QKV; barrier above guarantees done)
        #pragma unroll
        for (int nt = 0; nt < 2; ++nt) {
            float rr = __shfl(rl, 16 * nt + (lane & 15), 64);
            int sg = 32 * wi + 16 * nt + (lane & 15);
            const f32x4& acc = nt ? ao1 : ao0;
            unsigned int lo = (unsigned)f2bf(acc[0] * rr) | ((unsigned)f2bf(acc[1] * rr) << 16);
            unsigned int hi = (unsigned)f2bf(acc[2] * rr) | ((unsigned)f2bf(acc[3] * rr) << 16);
            uint2 pk2; pk2.x = lo; pk2.y = hi;
            *(uint2*)&y_s[sg][16 * h + 4 * qd] = pk2;
        }
        __syncthreads();   // protect q_s/k_s/vT_s (and y_s writes) before next head
    }

    // ---- single contiguous 32KB AO store ----
    unsigned short* ab = AO + (size_t)(n0 * 128 + w) * 128 * 128;
    #pragma unroll
    for (int i = 0; i < 8; ++i) {
        int idx = tid + 256 * i;
        *(int4*)(ab + (size_t)idx * 8) = *(const int4*)&y_s[idx >> 4][8 * (idx & 15)];
    }
}

// ---------------- K2: out-projection ----------------
// out[n0][e][s][w] = sum_c Wo[e][c] * AO[(n0*128+w)][s][c] + bo[e]
__global__ __launch_bounds__(256, 2) void axattn_proj(
    const unsigned short* __restrict__ AO,
    const float* __restrict__ Wo,
    const float* __restrict__ bo,
    float* __restrict__ out)
{
    __shared__ __align__(16) unsigned short ao_s[128][136];  // [w][c]
    __shared__ __align__(16) unsigned short wo_s[128][136];  // [e][c]

    int n0 = blockIdx.x >> 7;
    int s  = blockIdx.x & 127;
    int tid = threadIdx.x, lane = tid & 63, wi = tid >> 6;

    // stage AO rows (bf16, b128) + Wo (fp32 -> bf16, coalesced)
    #pragma unroll
    for (int i = 0; i < 8; ++i) {
        int idx = tid + 256 * i;
        int ww = idx >> 4;
        int ch = idx & 15;
        *(int4*)&ao_s[ww][8 * ch] =
            *(const int4*)(AO + (((size_t)(n0 * 128 + ww) * 128) + s) * 128 + 8 * ch);
    }
    #pragma unroll
    for (int i = 0; i < 16; ++i) {
        int idx = tid + 256 * i;
        int e  = idx >> 5;
        int c4 = idx & 31;
        float4 v = *(const float4*)(Wo + (size_t)e * 128 + 4 * c4);
        unsigned int lo = (unsigned)f2bf(v.x) | ((unsigned)f2bf(v.y) << 16);
        unsigned int hi = (unsigned)f2bf(v.z) | ((unsigned)f2bf(v.w) << 16);
        uint2 pk2; pk2.x = lo; pk2.y = hi;
        *(uint2*)&wo_s[e][4 * c4] = pk2;
    }
    __syncthreads();

    int m  = lane & 31;
    int kh = lane >> 5;
    int e  = 32 * wi + m;

    f32x16 acc[4];
    #pragma unroll
    for (int nt = 0; nt < 4; ++nt) {
        #pragma unroll
        for (int i = 0; i < 16; ++i) acc[nt][i] = 0.f;
    }

    #pragma unroll
    for (int kt = 0; kt < 8; ++kt) {
        int c0 = 16 * kt + 8 * kh;
        bf16x8 afrag = *(bf16x8*)&wo_s[e][c0];
        #pragma unroll
        for (int nt = 0; nt < 4; ++nt) {
            bf16x8 bfrag = *(bf16x8*)&ao_s[32 * nt + m][c0];
            acc[nt] = __builtin_amdgcn_mfma_f32_32x32x16_bf16(afrag, bfrag, acc[nt], 0, 0, 0);
        }
    }

    #pragma unroll
    for (int rg = 0; rg < 16; ++rg) {
        int er = 32 * wi + (rg & 3) + 8 * (rg >> 2) + 4 * kh;
        float bv = bo[er];
        size_t rowbase = (((size_t)(n0 * 128 + er) * 128) + s) * 128;
        #pragma unroll
        for (int nt = 0; nt < 4; ++nt) {
            out[rowbase + 32 * nt + m] = acc[nt][rg] + bv;
        }
    }
}

extern "C" void kernel_launch(void* const* d_in, const int* in_sizes, int n_in,
                              void* d_out, int out_size, void* d_ws, size_t ws_size,
                              hipStream_t stream) {
    const float* x  = (const float*)d_in[0];
    const float* Wq = (const float*)d_in[1];
    const float* Wk = (const float*)d_in[2];
    const float* Wv = (const float*)d_in[3];
    const float* Wo = (const float*)d_in[4];
    const float* bo = (const float*)d_in[5];
    float* out = (float*)d_out;

    unsigned short* Yt = (unsigned short*)d_ws;                       // 32 MiB bf16 [n0][w][s][c]
    unsigned short* AO = Yt + (size_t)8 * 128 * 128 * 128;            // 32 MiB bf16 [b][s][c]

    axattn_transpose<<<1024, 256, 0, stream>>>(x, Yt);
    axattn_qkvattn<<<1024, 256, 0, stream>>>(Yt, Wq, Wk, Wv, AO);
    axattn_proj<<<1024, 256, 0, stream>>>(AO, Wo, bo, out);
}

// Round 5
// 697.325 us; speedup vs baseline: 1.2986x; 1.2986x over previous
//
#include <hip/hip_runtime.h>
#include <hip/hip_bf16.h>

// AxialAttention on MI355X — bf16 MFMA pipeline, fully coalesced memory.
// T0: transpose x [n0][c][s][w] fp32 -> Y [n0][w][s][c] bf16 (LDS tile transpose).
// K1: per (n0,w): contiguous 32KB y load; per head: VALU QKV -> per-32j-tile
//     {E-tile MFMA -> exp -> pack -> PV MFMA} (only ONE f32x16 live -> no scratch);
//     1/l applied post-PV (exact). AO into aliased y_s; one contiguous 32KB store.
// K2: out-proj per (n0,s): Wo staged in LDS bf16; D = Wo*AO^T via mfma 32x32x16.

typedef __attribute__((ext_vector_type(8)))  short bf16x8;
typedef __attribute__((ext_vector_type(4)))  float f32x4;
typedef __attribute__((ext_vector_type(16))) float f32x16;

__device__ __forceinline__ float bf2f(unsigned short u) {
    union { unsigned int i; float f; } c; c.i = ((unsigned int)u) << 16; return c.f;
}
__device__ __forceinline__ unsigned short f2bf(float f) {
    union { __hip_bfloat16 h; unsigned short u; } c; c.h = __float2bfloat16(f); return c.u;
}

#define INV_SCALE 0.088388347648318447f   // 1/sqrt(128)

// ---------------- T0: x -> Y (bf16, transposed) ----------------
__global__ __launch_bounds__(256) void axattn_transpose(
    const float* __restrict__ x,
    unsigned short* __restrict__ Y)
{
    int n0 = blockIdx.x >> 7;
    int s  = blockIdx.x & 127;
    __shared__ unsigned int t_s[128][65];   // [w][c_pair], 2 bf16 packed

    int tid = threadIdx.x;
    int wl  = tid & 31;
    int g   = tid >> 5;

    const float* xp = x + ((size_t)(n0 * 128 + 16 * g) * 128 + s) * 128 + 4 * wl;
    #pragma unroll
    for (int i = 0; i < 16; i += 2) {
        float4 a = *(const float4*)(xp + (size_t)(i + 0) * 16384);
        float4 b = *(const float4*)(xp + (size_t)(i + 1) * 16384);
        int cp = 8 * g + (i >> 1);
        t_s[4 * wl + 0][cp] = (unsigned)f2bf(a.x) | ((unsigned)f2bf(b.x) << 16);
        t_s[4 * wl + 1][cp] = (unsigned)f2bf(a.y) | ((unsigned)f2bf(b.y) << 16);
        t_s[4 * wl + 2][cp] = (unsigned)f2bf(a.z) | ((unsigned)f2bf(b.z) << 16);
        t_s[4 * wl + 3][cp] = (unsigned)f2bf(a.w) | ((unsigned)f2bf(b.w) << 16);
    }
    __syncthreads();

    #pragma unroll
    for (int i = 0; i < 8; ++i) {
        int idx = tid + 256 * i;
        int w   = idx >> 4;
        int cp4 = idx & 15;
        uint4 v;
        v.x = t_s[w][4 * cp4 + 0];
        v.y = t_s[w][4 * cp4 + 1];
        v.z = t_s[w][4 * cp4 + 2];
        v.w = t_s[w][4 * cp4 + 3];
        *(uint4*)(Y + (((size_t)(n0 * 128 + w) * 128) + s) * 128 + 8 * cp4) = v;
    }
}

// ---------------- K1: QKV + attention ----------------
__global__ __launch_bounds__(256, 2) void axattn_qkvattn(
    const unsigned short* __restrict__ Y,
    const float* __restrict__ Wq,
    const float* __restrict__ Wk,
    const float* __restrict__ Wv,
    unsigned short* __restrict__ AO)
{
    __shared__ __align__(16) unsigned short y_s[128][136];  // [s][c]; AO aliased per head
    __shared__ __align__(16) unsigned short q_s[128][24];   // [s][e]
    __shared__ __align__(16) unsigned short k_s[128][24];   // [s][e]
    __shared__ __align__(16) unsigned short vT_s[16][136];  // [d][j]
    __shared__ __align__(16) unsigned short pT_s[4][32][40];// per-wave [s_local][j_local]

    int n0 = blockIdx.x >> 7;
    int w  = blockIdx.x & 127;

    int tid  = threadIdx.x;
    int lane = tid & 63;
    int wi   = tid >> 6;

    // ---- stage y (contiguous, coalesced b128) ----
    const unsigned short* ybase = Y + (size_t)(n0 * 128 + w) * 128 * 128;
    #pragma unroll
    for (int i = 0; i < 8; ++i) {
        int idx = tid + 256 * i;
        *(int4*)&y_s[idx >> 4][8 * (idx & 15)] = *(const int4*)(ybase + (size_t)idx * 8);
    }
    __syncthreads();

    for (int h = 0; h < 8; ++h) {
        // ---- QKV (VALU): thread -> (s = tid&127, eh = tid>>7 wave-uniform) ----
        {
            int s  = tid & 127;
            int eh = tid >> 7;
            float yv[16];
            union { unsigned short u[8]; int4 v; } ya, yb2;
            ya.v  = *(const int4*)&y_s[s][16 * h];
            yb2.v = *(const int4*)&y_s[s][16 * h + 8];
            #pragma unroll
            for (int d = 0; d < 8; ++d) { yv[d] = bf2f(ya.u[d]); yv[d + 8] = bf2f(yb2.u[d]); }

            float qa[8], ka[8], va[8];
            #pragma unroll
            for (int j = 0; j < 8; ++j) { qa[j] = 0.f; ka[j] = 0.f; va[j] = 0.f; }
            #pragma unroll
            for (int d = 0; d < 16; ++d) {
                float yd = yv[d];
                #pragma unroll
                for (int j = 0; j < 8; ++j) {
                    int e = 8 * eh + j;
                    qa[j] = fmaf(yd, Wq[e * 16 + d], qa[j]);
                    ka[j] = fmaf(yd, Wk[e * 16 + d], ka[j]);
                    va[j] = fmaf(yd, Wv[e * 16 + d], va[j]);
                }
            }
            union { unsigned short u[8]; int4 v; } pq, pk;
            #pragma unroll
            for (int j = 0; j < 8; ++j) {
                pq.u[j] = f2bf(qa[j] * INV_SCALE);
                pk.u[j] = f2bf(ka[j]);
            }
            *(int4*)&q_s[s][8 * eh] = pq.v;
            *(int4*)&k_s[s][8 * eh] = pk.v;
            #pragma unroll
            for (int j = 0; j < 8; ++j) vT_s[8 * eh + j][s] = f2bf(va[j]);
        }
        __syncthreads();

        int sl = lane & 31;
        int kh = lane >> 5;
        int qd = lane >> 4;
        int md = lane & 15;

        bf16x8 qfrag = *(bf16x8*)&q_s[32 * wi + sl][8 * kh];

        f32x4 ao0, ao1;
        #pragma unroll
        for (int i = 0; i < 4; ++i) { ao0[i] = 0.f; ao1[i] = 0.f; }
        float lsum = 0.f;

        // ---- fused per-32j-tile: E MFMA -> exp -> pack -> PV MFMA ----
        // only ONE f32x16 live at a time -> no scratch spills.
        #pragma unroll
        for (int jt = 0; jt < 4; ++jt) {
            bf16x8 kfrag = *(bf16x8*)&k_s[32 * jt + sl][8 * kh];
            f32x16 z;
            #pragma unroll
            for (int i = 0; i < 16; ++i) z[i] = 0.f;
            f32x16 ev = __builtin_amdgcn_mfma_f32_32x32x16_bf16(kfrag, qfrag, z, 0, 0, 0);

            float p[16];
            #pragma unroll
            for (int i = 0; i < 16; ++i) p[i] = __expf(ev[i]);
            #pragma unroll
            for (int i = 0; i < 16; ++i) lsum += p[i];

            // reg r -> j_local = (r&3) + 8*(r>>2) + 4*kh; pack consecutive-j pairs
            #pragma unroll
            for (int a = 0; a < 4; ++a) {
                #pragma unroll
                for (int b = 0; b < 4; b += 2) {
                    int r0 = 4 * a + b;
                    unsigned int lo = f2bf(p[r0]);
                    unsigned int hi = f2bf(p[r0 + 1]);
                    *(unsigned int*)&pT_s[wi][sl][8 * a + b + 4 * kh] = lo | (hi << 16);
                }
            }
            bf16x8 afrag = *(bf16x8*)&vT_s[md][32 * jt + 8 * qd];
            bf16x8 b0 = *(bf16x8*)&pT_s[wi][md][8 * qd];
            bf16x8 b1 = *(bf16x8*)&pT_s[wi][16 + md][8 * qd];
            ao0 = __builtin_amdgcn_mfma_f32_16x16x32_bf16(afrag, b0, ao0, 0, 0, 0);
            ao1 = __builtin_amdgcn_mfma_f32_16x16x32_bf16(afrag, b1, ao1, 0, 0, 0);
        }

        lsum += __shfl_xor(lsum, 32, 64);
        float rl = 1.0f / lsum;

        // ---- scale by 1/l, write AO fragment into aliased y_s columns of head h ----
        #pragma unroll
        for (int nt = 0; nt < 2; ++nt) {
            float rr = __shfl(rl, 16 * nt + md, 64);
            int sg = 32 * wi + 16 * nt + md;
            const f32x4& acc = nt ? ao1 : ao0;
            unsigned int lo = (unsigned)f2bf(acc[0] * rr) | ((unsigned)f2bf(acc[1] * rr) << 16);
            unsigned int hi = (unsigned)f2bf(acc[2] * rr) | ((unsigned)f2bf(acc[3] * rr) << 16);
            uint2 pk2; pk2.x = lo; pk2.y = hi;
            *(uint2*)&y_s[sg][16 * h + 4 * qd] = pk2;
        }
        __syncthreads();   // protect q_s/k_s/vT_s (and y_s writes) before next head
    }

    // ---- single contiguous 32KB AO store ----
    unsigned short* ab = AO + (size_t)(n0 * 128 + w) * 128 * 128;
    #pragma unroll
    for (int i = 0; i < 8; ++i) {
        int idx = tid + 256 * i;
        *(int4*)(ab + (size_t)idx * 8) = *(const int4*)&y_s[idx >> 4][8 * (idx & 15)];
    }
}

// ---------------- K2: out-projection ----------------
// out[n0][e][s][w] = sum_c Wo[e][c] * AO[(n0*128+w)][s][c] + bo[e]
__global__ __launch_bounds__(256, 2) void axattn_proj(
    const unsigned short* __restrict__ AO,
    const float* __restrict__ Wo,
    const float* __restrict__ bo,
    float* __restrict__ out)
{
    __shared__ __align__(16) unsigned short ao_s[128][136];  // [w][c]
    __shared__ __align__(16) unsigned short wo_s[128][136];  // [e][c]

    int n0 = blockIdx.x >> 7;
    int s  = blockIdx.x & 127;
    int tid = threadIdx.x, lane = tid & 63, wi = tid >> 6;

    #pragma unroll
    for (int i = 0; i < 8; ++i) {
        int idx = tid + 256 * i;
        int ww = idx >> 4;
        int ch = idx & 15;
        *(int4*)&ao_s[ww][8 * ch] =
            *(const int4*)(AO + (((size_t)(n0 * 128 + ww) * 128) + s) * 128 + 8 * ch);
    }
    #pragma unroll
    for (int i = 0; i < 16; ++i) {
        int idx = tid + 256 * i;
        int e  = idx >> 5;
        int c4 = idx & 31;
        float4 v = *(const float4*)(Wo + (size_t)e * 128 + 4 * c4);
        unsigned int lo = (unsigned)f2bf(v.x) | ((unsigned)f2bf(v.y) << 16);
        unsigned int hi = (unsigned)f2bf(v.z) | ((unsigned)f2bf(v.w) << 16);
        uint2 pk2; pk2.x = lo; pk2.y = hi;
        *(uint2*)&wo_s[e][4 * c4] = pk2;
    }
    __syncthreads();

    int m  = lane & 31;
    int kh = lane >> 5;
    int e  = 32 * wi + m;

    f32x16 acc[4];
    #pragma unroll
    for (int nt = 0; nt < 4; ++nt) {
        #pragma unroll
        for (int i = 0; i < 16; ++i) acc[nt][i] = 0.f;
    }

    #pragma unroll
    for (int kt = 0; kt < 8; ++kt) {
        int c0 = 16 * kt + 8 * kh;
        bf16x8 afrag = *(bf16x8*)&wo_s[e][c0];
        #pragma unroll
        for (int nt = 0; nt < 4; ++nt) {
            bf16x8 bfrag = *(bf16x8*)&ao_s[32 * nt + m][c0];
            acc[nt] = __builtin_amdgcn_mfma_f32_32x32x16_bf16(afrag, bfrag, acc[nt], 0, 0, 0);
        }
    }

    #pragma unroll
    for (int rg = 0; rg < 16; ++rg) {
        int er = 32 * wi + (rg & 3) + 8 * (rg >> 2) + 4 * kh;
        float bv = bo[er];
        size_t rowbase = (((size_t)(n0 * 128 + er) * 128) + s) * 128;
        #pragma unroll
        for (int nt = 0; nt < 4; ++nt) {
            out[rowbase + 32 * nt + m] = acc[nt][rg] + bv;
        }
    }
}

extern "C" void kernel_launch(void* const* d_in, const int* in_sizes, int n_in,
                              void* d_out, int out_size, void* d_ws, size_t ws_size,
                              hipStream_t stream) {
    const float* x  = (const float*)d_in[0];
    const float* Wq = (const float*)d_in[1];
    const float* Wk = (const float*)d_in[2];
    const float* Wv = (const float*)d_in[3];
    const float* Wo = (const float*)d_in[4];
    const float* bo = (const float*)d_in[5];
    float* out = (float*)d_out;

    unsigned short* Yt = (unsigned short*)d_ws;             // 32 MiB bf16 [n0][w][s][c]
    unsigned short* AO = Yt + (size_t)8 * 128 * 128 * 128;  // 32 MiB bf16 [b][s][c]

    axattn_transpose<<<1024, 256, 0, stream>>>(x, Yt);
    axattn_qkvattn<<<1024, 256, 0, stream>>>(Yt, Wq, Wk, Wv, AO);
    axattn_proj<<<1024, 256, 0, stream>>>(AO, Wo, bo, out);
}